// Round 11
// baseline (161.214 us; speedup 1.0000x reference)
//
#include <hip/hip_runtime.h>
#include <hip/hip_bf16.h>

#define N_NODES 50000
#define N_EDGES 640000

typedef __attribute__((ext_vector_type(8))) short bf16x8;
typedef __attribute__((ext_vector_type(4))) float f32x4;

static __device__ __forceinline__ short f2bf(float f) {
    __hip_bfloat16 h = __float2bfloat16(f);
    return *reinterpret_cast<const short*>(&h);
}

static __device__ __forceinline__ float sgpr_f(const float* p) {
    return __uint_as_float(__builtin_amdgcn_readfirstlane(__float_as_uint(*p)));
}

__global__ __launch_bounds__(256, 8)   // force <=64 VGPR -> 8 waves/SIMD
void edge_hyper_kernel(const float* __restrict__ x,
                       const int* __restrict__ ei,      // int32 [2][E]
                       const float* __restrict__ ev,
                       const float* __restrict__ nrm,
                       const float* __restrict__ W1,
                       const float* __restrict__ b1,
                       const float* __restrict__ W2,
                       const float* __restrict__ b2,
                       float* __restrict__ out,
                       int ngroups)
{
    // B tiles in LDS: [c][o][k] bf16, k-row padded 32->34 (2-way aliasing free).
    __shared__ short w2s[17 * 16 * 34];

    const int tid  = threadIdx.x;
    const int l    = tid & 63;
    const int r    = l & 15;         // A-row edge-in-group / D col o
    const int half = l >> 4;         // 0..3 -> k-range half*8..half*8+7

    // ---- cooperative W2/b2 -> bf16 LDS (c=16 is the b2 bias tile) ----
    for (int idx = tid; idx < 17 * 512; idx += 256) {
        const int c   = idx >> 9;
        const int rem = idx & 511;
        const int o   = rem >> 5;
        const int k   = rem & 31;
        const float v = (c < 16) ? W2[c * 512 + o * 32 + k] : b2[o * 32 + k];
        w2s[(c * 16 + o) * 34 + k] = f2bf(v);
    }

    // ---- W1/b1 pinned to SGPRs ----
    float w1c0[16], w1c1[16], w1c2[16], b1s[16];
    #pragma unroll
    for (int c = 0; c < 16; ++c) {
        w1c0[c] = sgpr_f(W1 + c);
        w1c1[c] = sgpr_f(W1 + 16 + c);
        w1c2[c] = sgpr_f(W1 + 32 + c);
        b1s[c]  = sgpr_f(b1 + c);
    }

    __syncthreads();   // w2s ready; no further sync

    // per-lane LDS base: tile c element (c*16+r)*34 + half*8  ->  wbase + c*544
    const short* wbase = &w2s[r * 34 + half * 8];

    const int wv = tid >> 6;
    int g = blockIdx.x * 4 + wv;
    const int nw = gridDim.x * 4;
    if (g >= ngroups) return;

    const int eisel = (half >= 2 ? N_EDGES : 0);

    // ---- pipeline prologue ----
    // current group g: all data incl. x; group g+nw: scalar loads incl. idx.
    float  e0_c, e1_c, e2_c;
    float4 xa_c, xb_c, nr_c;
    int4   dst_c;
    int    idx_p1;                       // idx for group g+nw (x not yet gathered)
    float  e0_p1, e1_p1, e2_p1;
    float4 nr_p1;
    int4   dst_p1;
    {
        const int e0 = g * 16;
        const int idx0 = ei[eisel + e0 + r];
        const float* evp = ev + (size_t)(e0 + r) * 3;
        e0_c = evp[0]; e1_c = evp[1]; e2_c = evp[2];
        nr_c  = *reinterpret_cast<const float4*>(nrm + e0 + half * 4);
        dst_c = *reinterpret_cast<const int4*>(ei + N_EDGES + e0 + half * 4);
        const float4* xr = reinterpret_cast<const float4*>(
            x + (size_t)idx0 * 16 + (half & 1) * 8);
        xa_c = xr[0];
        xb_c = xr[1];
    }
    {
        const int gp1 = (g + nw < ngroups) ? g + nw : g;
        const int e0p = gp1 * 16;
        idx_p1 = ei[eisel + e0p + r];
        const float* evp = ev + (size_t)(e0p + r) * 3;
        e0_p1 = evp[0]; e1_p1 = evp[1]; e2_p1 = evp[2];
        nr_p1  = *reinterpret_cast<const float4*>(nrm + e0p + half * 4);
        dst_p1 = *reinterpret_cast<const int4*>(ei + N_EDGES + e0p + half * 4);
    }

    while (g < ngroups) {
        // ---- (1) issue 2-ahead idx load + 1-ahead-refresh scalar loads ----
        const int gp2v = g + 2 * nw;
        const int gp2  = (gp2v < ngroups) ? gp2v : g;    // clamp: reload current
        const int e0p2 = gp2 * 16;
        const int idx_p2 = ei[eisel + e0p2 + r];
        const float* evp2 = ev + (size_t)(e0p2 + r) * 3;
        const float e0_p2 = evp2[0], e1_p2 = evp2[1], e2_p2 = evp2[2];
        const float4 nr_p2  = *reinterpret_cast<const float4*>(nrm + e0p2 + half * 4);
        const int4   dst_p2 = *reinterpret_cast<const int4*>(ei + N_EDGES + e0p2 + half * 4);

        // ---- (2) issue 1-ahead x gather from ALREADY-RESIDENT idx_p1 ----
        const float4* xr1 = reinterpret_cast<const float4*>(
            x + (size_t)idx_p1 * 16 + (half & 1) * 8);
        const float4 xa_p1 = xr1[0];
        const float4 xb_p1 = xr1[1];

        // ---- (3) plain bf16 xe fragment (bias tile A-operand) ----
        bf16x8 afrag;
        afrag[0] = f2bf(xa_c.x); afrag[1] = f2bf(xa_c.y);
        afrag[2] = f2bf(xa_c.z); afrag[3] = f2bf(xa_c.w);
        afrag[4] = f2bf(xb_c.x); afrag[5] = f2bf(xb_c.y);
        afrag[6] = f2bf(xb_c.z); afrag[7] = f2bf(xb_c.w);

        // ---- (4) bias tile (c=16): acc = xe @ b2^T ----
        f32x4 accA, accB;
        {
            const bf16x8 bfr = *reinterpret_cast<const bf16x8*>(wbase + 16 * 544);
            accA = __builtin_amdgcn_mfma_f32_16x16x32_bf16(
                afrag, bfr, (f32x4){0.f, 0.f, 0.f, 0.f}, 0, 0, 0);
        }
        accB = (f32x4){0.f, 0.f, 0.f, 0.f};

        // ---- (5) 16 c-tiles: h inline (no h[] array), A = h*xe, MFMA acc ----
        #pragma unroll
        for (int c = 0; c < 16; ++c) {
            const bf16x8 bfr = *reinterpret_cast<const bf16x8*>(wbase + c * 544);
            float hc = fmaf(e2_c, w1c2[c],
                       fmaf(e1_c, w1c1[c],
                       fmaf(e0_c, w1c0[c], b1s[c])));
            hc = fmaxf(hc, 0.0f);
            bf16x8 yf;
            yf[0] = f2bf(hc * xa_c.x); yf[1] = f2bf(hc * xa_c.y);
            yf[2] = f2bf(hc * xa_c.z); yf[3] = f2bf(hc * xa_c.w);
            yf[4] = f2bf(hc * xb_c.x); yf[5] = f2bf(hc * xb_c.y);
            yf[6] = f2bf(hc * xb_c.z); yf[7] = f2bf(hc * xb_c.w);
            if (c & 1)
                accB = __builtin_amdgcn_mfma_f32_16x16x32_bf16(yf, bfr, accB, 0, 0, 0);
            else
                accA = __builtin_amdgcn_mfma_f32_16x16x32_bf16(yf, bfr, accA, 0, 0, 0);
        }

        // ---- (6) epilogue: tanh, norm scale, f32 scatter-add ----
        // D layout (m89-verified): col = l&15 (=o=r), row = half*4+q (=edge)
        const float nrv[4] = {nr_c.x, nr_c.y, nr_c.z, nr_c.w};
        const int   dsv[4] = {dst_c.x, dst_c.y, dst_c.z, dst_c.w};
        #pragma unroll
        for (int q = 0; q < 4; ++q) {
            const float sv = accA[q] + accB[q];
            const float t  = __expf(-2.0f * fabsf(sv));
            const float th = copysignf((1.0f - t) * __builtin_amdgcn_rcpf(1.0f + t), sv);
            atomicAdd(out + (size_t)dsv[q] * 16 + r, th * nrv[q]);
        }

        // ---- (7) rotate pipeline state ----
        xa_c = xa_p1; xb_c = xb_p1;
        e0_c = e0_p1; e1_c = e1_p1; e2_c = e2_p1;
        nr_c = nr_p1; dst_c = dst_p1;
        idx_p1 = idx_p2;
        e0_p1 = e0_p2; e1_p1 = e1_p2; e2_p1 = e2_p2;
        nr_p1 = nr_p2; dst_p1 = dst_p2;
        g += nw;
    }
}

extern "C" void kernel_launch(void* const* d_in, const int* in_sizes, int n_in,
                              void* d_out, int out_size, void* d_ws, size_t ws_size,
                              hipStream_t stream) {
    const float* x   = (const float*)d_in[0];
    const int*   ei  = (const int*)d_in[1];
    const float* ev  = (const float*)d_in[2];
    const float* nrm = (const float*)d_in[3];
    const float* W1  = (const float*)d_in[4];
    const float* b1  = (const float*)d_in[5];
    const float* W2  = (const float*)d_in[6];
    const float* b2  = (const float*)d_in[7];
    float* out = (float*)d_out;

    hipMemsetAsync(out, 0, (size_t)out_size * sizeof(float), stream);

    const int ngroups = N_EDGES / 16;   // 40000, exact
    dim3 grid(2048), block(256);
    hipLaunchKernelGGL(edge_hyper_kernel, grid, block, 0, stream,
                       x, ei, ev, nrm, W1, b1, W2, b2, out, ngroups);
}

// Round 12
// 54.099 us; speedup vs baseline: 2.9800x; 2.9800x over previous
//
#include <hip/hip_runtime.h>
#include <hip/hip_bf16.h>

#define N_NODES 50000
#define N_EDGES 640000

typedef __attribute__((ext_vector_type(8))) short bf16x8;
typedef __attribute__((ext_vector_type(4))) float f32x4;

static __device__ __forceinline__ short f2bf(float f) {
    __hip_bfloat16 h = __float2bfloat16(f);
    return *reinterpret_cast<const short*>(&h);
}

static __device__ __forceinline__ float sgpr_f(const float* p) {
    return __uint_as_float(__builtin_amdgcn_readfirstlane(__float_as_uint(*p)));
}

// ---- tiny pre-pass: W2/b2 f32 -> bf16 table in d_ws (17 tiles x 512) ----
// layout: w2bf[(c*16 + o)*32 + k], c=16 is the b2 bias tile.
__global__ __launch_bounds__(256)
void w2_convert_kernel(const float* __restrict__ W2,
                       const float* __restrict__ b2,
                       short* __restrict__ w2bf)
{
    const int i = blockIdx.x * 256 + threadIdx.x;   // 0 .. 17*512-1
    if (i >= 17 * 512) return;
    const int c   = i >> 9;
    const int rem = i & 511;
    w2bf[i] = f2bf(c < 16 ? W2[c * 512 + rem] : b2[rem]);
}

__global__ __launch_bounds__(256)
void edge_hyper_kernel(const float* __restrict__ x,
                       const int* __restrict__ ei,      // int32 [2][E]
                       const float* __restrict__ ev,
                       const float* __restrict__ nrm,
                       const float* __restrict__ W1,
                       const float* __restrict__ b1,
                       const short* __restrict__ w2bf,  // preconverted bf16 tiles
                       float* __restrict__ out,
                       int ngroups)
{
    const int tid  = threadIdx.x;
    const int l    = tid & 63;
    const int r    = l & 15;         // A-row edge-in-group / D col o
    const int half = l >> 4;         // 0..3 -> k-range half*8..half*8+7

    // ---- persistent B fragments in registers: 17 tiles x 16B/lane.
    // Whole table is 17 KiB -> L1-resident; loaded once per wave. ----
    bf16x8 bfrag[17];
    #pragma unroll
    for (int c = 0; c < 17; ++c) {
        bfrag[c] = *reinterpret_cast<const bf16x8*>(
            w2bf + ((c * 16 + r) * 32 + half * 8));
    }

    // ---- W1/b1 pinned to SGPRs ----
    float w1c0[16], w1c1[16], w1c2[16], b1s[16];
    #pragma unroll
    for (int c = 0; c < 16; ++c) {
        w1c0[c] = sgpr_f(W1 + c);
        w1c1[c] = sgpr_f(W1 + 16 + c);
        w1c2[c] = sgpr_f(W1 + 32 + c);
        b1s[c]  = sgpr_f(b1 + c);
    }

    const int wv = tid >> 6;
    int g = blockIdx.x * 4 + wv;        // nw=8192 <= ngroups: always has work
    const int nw = gridDim.x * 4;
    const int eisel = (half >= 2 ? N_EDGES : 0);

    // ---- pipeline prologue: group g fully loaded; g+nw idx+ev resident ----
    float  e0_c, e1_c, e2_c;
    float4 xa_c, xb_c;
    int    idx_p1;
    float  e0_p1, e1_p1, e2_p1;
    {
        const int e0 = g * 16;
        const int idx0 = ei[eisel + e0 + r];
        const float* evp = ev + (size_t)(e0 + r) * 3;
        e0_c = evp[0]; e1_c = evp[1]; e2_c = evp[2];
        const float4* xr = reinterpret_cast<const float4*>(
            x + (size_t)idx0 * 16 + (half & 1) * 8);
        xa_c = xr[0];
        xb_c = xr[1];
    }
    {
        const int gp1 = (g + nw < ngroups) ? g + nw : g;
        const int e0p = gp1 * 16;
        idx_p1 = ei[eisel + e0p + r];
        const float* evp = ev + (size_t)(e0p + r) * 3;
        e0_p1 = evp[0]; e1_p1 = evp[1]; e2_p1 = evp[2];
    }

    while (g < ngroups) {
        const int e0 = g * 16;

        // ---- (1) this group's epilogue data (latency hides under c-loop) ----
        const float4 nr_c  = *reinterpret_cast<const float4*>(nrm + e0 + half * 4);
        const int4   dst_c = *reinterpret_cast<const int4*>(ei + N_EDGES + e0 + half * 4);

        // ---- (2) 2-ahead idx + 1-ahead ev refresh ----
        const int gp2v = g + 2 * nw;
        const int gp2  = (gp2v < ngroups) ? gp2v : g;    // clamp: reload current
        const int e0p2 = gp2 * 16;
        const int idx_p2 = ei[eisel + e0p2 + r];
        const float* evp2 = ev + (size_t)(e0p2 + r) * 3;
        const float e0_p2 = evp2[0], e1_p2 = evp2[1], e2_p2 = evp2[2];

        // ---- (3) 1-ahead x gather from RESIDENT idx (no mid-iter dep) ----
        const float4* xr1 = reinterpret_cast<const float4*>(
            x + (size_t)idx_p1 * 16 + (half & 1) * 8);
        const float4 xa_p1 = xr1[0];
        const float4 xb_p1 = xr1[1];

        // ---- (4) plain bf16 xe fragment (bias tile A-operand) ----
        bf16x8 afrag;
        afrag[0] = f2bf(xa_c.x); afrag[1] = f2bf(xa_c.y);
        afrag[2] = f2bf(xa_c.z); afrag[3] = f2bf(xa_c.w);
        afrag[4] = f2bf(xb_c.x); afrag[5] = f2bf(xb_c.y);
        afrag[6] = f2bf(xb_c.z); afrag[7] = f2bf(xb_c.w);

        // ---- (5) bias tile (c=16): acc = xe @ b2^T ----
        f32x4 accA = __builtin_amdgcn_mfma_f32_16x16x32_bf16(
            afrag, bfrag[16], (f32x4){0.f, 0.f, 0.f, 0.f}, 0, 0, 0);
        f32x4 accB = (f32x4){0.f, 0.f, 0.f, 0.f};

        // ---- (6) 16 c-tiles: h inline, A = h*xe (YE), MFMA register-only ----
        #pragma unroll
        for (int c = 0; c < 16; ++c) {
            float hc = fmaf(e2_c, w1c2[c],
                       fmaf(e1_c, w1c1[c],
                       fmaf(e0_c, w1c0[c], b1s[c])));
            hc = fmaxf(hc, 0.0f);
            bf16x8 yf;
            yf[0] = f2bf(hc * xa_c.x); yf[1] = f2bf(hc * xa_c.y);
            yf[2] = f2bf(hc * xa_c.z); yf[3] = f2bf(hc * xa_c.w);
            yf[4] = f2bf(hc * xb_c.x); yf[5] = f2bf(hc * xb_c.y);
            yf[6] = f2bf(hc * xb_c.z); yf[7] = f2bf(hc * xb_c.w);
            if (c & 1)
                accB = __builtin_amdgcn_mfma_f32_16x16x32_bf16(yf, bfrag[c], accB, 0, 0, 0);
            else
                accA = __builtin_amdgcn_mfma_f32_16x16x32_bf16(yf, bfrag[c], accA, 0, 0, 0);
        }

        // ---- (7) epilogue: tanh, norm scale, f32 scatter-add ----
        // D layout (m89-verified): col = l&15 (=o=r), row = half*4+q (=edge)
        const float nrv[4] = {nr_c.x, nr_c.y, nr_c.z, nr_c.w};
        const int   dsv[4] = {dst_c.x, dst_c.y, dst_c.z, dst_c.w};
        #pragma unroll
        for (int q = 0; q < 4; ++q) {
            const float sv = accA[q] + accB[q];
            const float t  = __expf(-2.0f * fabsf(sv));
            const float th = copysignf((1.0f - t) * __builtin_amdgcn_rcpf(1.0f + t), sv);
            atomicAdd(out + (size_t)dsv[q] * 16 + r, th * nrv[q]);
        }

        // ---- (8) rotate pipeline state ----
        xa_c = xa_p1; xb_c = xb_p1;
        e0_c = e0_p1; e1_c = e1_p1; e2_c = e2_p1;
        idx_p1 = idx_p2;
        e0_p1 = e0_p2; e1_p1 = e1_p2; e2_p1 = e2_p2;
        g += nw;
    }
}

extern "C" void kernel_launch(void* const* d_in, const int* in_sizes, int n_in,
                              void* d_out, int out_size, void* d_ws, size_t ws_size,
                              hipStream_t stream) {
    const float* x   = (const float*)d_in[0];
    const int*   ei  = (const int*)d_in[1];
    const float* ev  = (const float*)d_in[2];
    const float* nrm = (const float*)d_in[3];
    const float* W1  = (const float*)d_in[4];
    const float* b1  = (const float*)d_in[5];
    const float* W2  = (const float*)d_in[6];
    const float* b2  = (const float*)d_in[7];
    float* out = (float*)d_out;
    short* w2bf = (short*)d_ws;          // 17*512*2 = 17408 B (ws is ~MBs)

    hipMemsetAsync(out, 0, (size_t)out_size * sizeof(float), stream);

    hipLaunchKernelGGL(w2_convert_kernel, dim3(34), dim3(256), 0, stream,
                       W2, b2, w2bf);

    const int ngroups = N_EDGES / 16;   // 40000, exact
    dim3 grid(2048), block(256);
    hipLaunchKernelGGL(edge_hyper_kernel, grid, block, 0, stream,
                       x, ei, ev, nrm, W1, b1, w2bf, out, ngroups);
}